// Round 7
// baseline (222.485 us; speedup 1.0000x reference)
//
#include <hip/hip_runtime.h>
#include <hip/hip_bf16.h>
#include <float.h>
#include <math.h>

#define NB 32
#define NPER 2000
#define EPER 16000
#define HID 256
#define EFD 20
#define ETN 3
#define CN 100
#define NTOT (NB*NPER)   // 64000
#define ETOT (NB*EPER)   // 512000

#define QDELTA (6.0f/127.0f)        // int8 quant step for Q/K1 (elems ~N(0,1))
#define QINV   (127.0f/6.0f)

using f32x4  = __attribute__((ext_vector_type(4))) float;
using bf16x8 = __attribute__((ext_vector_type(8))) short;
using ushort8= __attribute__((ext_vector_type(8))) unsigned short;
using u32x4  = __attribute__((ext_vector_type(4))) unsigned int;

__device__ __forceinline__ unsigned short f2bf(float f){
  union{float f; unsigned int i;}v; v.f=f; unsigned int x=v.i;
  return (unsigned short)((x + 0x7fffu + ((x>>16)&1u)) >> 16);
}
__device__ __forceinline__ unsigned int cvt_pk_bf16(float lo, float hi){
  unsigned int r;
  asm("v_cvt_pk_bf16_f32 %0, %1, %2" : "=v"(r) : "v"(lo), "v"(hi));
  return r;
}
__device__ __forceinline__ void dot4i8(int& acc, unsigned int a, unsigned int b){
  asm("v_dot4_i32_i8 %0, %1, %2, %0" : "+v"(acc) : "v"(a), "v"(b));
}
__device__ __forceinline__ int sel4(int4 v, int i){
  int r = v.x;
  r = (i==1) ? v.y : r;
  r = (i==2) ? v.z : r;
  r = (i==3) ? v.w : r;
  return r;
}
__device__ __forceinline__ int sel8(int4 a, int4 b, int i){
  int lo = sel4(a, i&3);
  int hi = sel4(b, i&3);
  return (i&4) ? hi : lo;
}

// ---- setup: zero seg/out0; swizzle-convert Wl/Wr -> bf16 frag layout; k2 -> int8.
// seg layout: seg[2n] = sum(ex), seg[2n+1] = sum(ex*score)
__global__ __launch_bounds__(256) void setup_kernel(
    const float* __restrict__ Wl, const float* __restrict__ Wr,
    const float* __restrict__ We, const float* __restrict__ be,
    const float* __restrict__ edge_emb,
    unsigned short* __restrict__ Wlsw, unsigned short* __restrict__ Wrsw,
    signed char* __restrict__ k2q, float* __restrict__ k2scale,
    float* __restrict__ seg, float* __restrict__ out)
{
  __shared__ float k2f[ETN*HID];
  __shared__ float redmax[256];
  int b = blockIdx.x, t = threadIdx.x;
  if (b < 500) {
    int i = b*256 + t;            // 0..127999 = 2*NTOT
    seg[i] = 0.0f;
    if (i == 0) out[0] = 0.0f;
  } else if (b < 564) {
    int u = (b-500)*256 + t;       // 0..16383 units of 8 elems
    int mat  = u >> 13;
    int v    = u & 8191;
    int cblk = v >> 9;
    int r    = v & 511;
    int kblk = r >> 6;
    int lane = r & 63;
    int col  = (cblk<<4) | (lane&15);
    int kk   = (kblk<<5) | ((lane>>4)<<3);
    const float* Wsrc = mat ? Wr : Wl;
    const f32x4* p = (const f32x4*)(Wsrc + col*HID + kk);
    f32x4 x0 = p[0], x1 = p[1];
    ushort8 w;
    w[0]=f2bf(x0[0]); w[1]=f2bf(x0[1]); w[2]=f2bf(x0[2]); w[3]=f2bf(x0[3]);
    w[4]=f2bf(x1[0]); w[5]=f2bf(x1[1]); w[6]=f2bf(x1[2]); w[7]=f2bf(x1[3]);
    *(ushort8*)((mat ? Wrsw : Wlsw) + (size_t)v*8) = w;
  } else {
    int j = t;
    float lmax = 0.0f;
    for (int ty=0; ty<ETN; ty++){
      float acc = be[j];
      for (int f=0; f<EFD; f++){
        float x = edge_emb[ty*EFD+f];
        float g = 0.5f*x*(1.0f + erff(x*0.7071067811865476f));
        acc += g * We[j*EFD+f];
      }
      k2f[ty*HID + j] = acc;
      lmax = fmaxf(lmax, fabsf(acc));
    }
    redmax[t] = lmax; __syncthreads();
    for (int sd=128; sd>0; sd>>=1){
      if (t < sd) redmax[t] = fmaxf(redmax[t], redmax[t+sd]);
      __syncthreads();
    }
    float d2 = fmaxf(redmax[0], 1e-20f) * (1.0f/127.0f);
    for (int ty=0; ty<ETN; ty++){
      int qv = (int)rintf(k2f[ty*HID+j] / d2);
      qv = min(127, max(-127, qv));
      k2q[ty*HID + j] = (signed char)qv;
    }
    if (t == 0) k2scale[0] = d2;
  }
}

// Q = h@Wl^T+bl ; K1 = h@Wr^T+br -> int8. NO LDS, NO BARRIERS.
// Block = 256 rows x 64-col slice; 8 waves each own 32 rows x 64 cols of both.
// A-fragments gathered directly from global h (read once, L3/L2-served);
// W-fragments identical across the 8 waves -> L1 broadcast.
__global__ __launch_bounds__(512) void gemm_qk(
    const float* __restrict__ h,
    const unsigned short* __restrict__ Wlsw, const unsigned short* __restrict__ Wrsw,
    const float* __restrict__ bl, const float* __restrict__ br,
    signed char* __restrict__ Qi8, signed char* __restrict__ K1i8)
{
  int bid = blockIdx.x;          // 0..999, col-slice fastest (L3 hit on shared h rows)
  int rc = bid >> 2;             // 0..249 row chunk of 256
  int cs = bid & 3;              // 0..3  col slice of 64
  int tid = threadIdx.x;
  int lane = tid & 63;
  int wv = tid >> 6;             // 0..7

  int rowf = rc*256 + wv*32 + (lane&15);   // fragment row (+fm*16)
  int kb_lane = (lane>>4)*8;
  int C0 = cs*64;

  f32x4 accQ[2][4], accK[2][4];
  #pragma unroll
  for(int i=0;i<2;i++)
    #pragma unroll
    for(int j=0;j<4;j++)
      #pragma unroll
      for(int r=0;r<4;r++){ accQ[i][j][r]=0.0f; accK[i][j][r]=0.0f; }

  #pragma unroll
  for (int kblk = 0; kblk < 8; ++kblk) {
    int k0 = kblk*32 + kb_lane;
    bf16x8 af[2], lf[4], rf[4];
    #pragma unroll
    for (int fm=0; fm<2; fm++){
      const float* p = h + (size_t)(rowf + fm*16)*HID + k0;
      f32x4 x0 = *(const f32x4*)p;
      f32x4 x1 = *(const f32x4*)(p + 4);
      u32x4 aw;
      aw[0] = cvt_pk_bf16(x0[0], x0[1]);
      aw[1] = cvt_pk_bf16(x0[2], x0[3]);
      aw[2] = cvt_pk_bf16(x1[0], x1[1]);
      aw[3] = cvt_pk_bf16(x1[2], x1[3]);
      af[fm] = *(bf16x8*)&aw;
    }
    #pragma unroll
    for (int fn=0; fn<4; fn++){
      size_t o = ((size_t)((cs*4 + fn)*8 + kblk)*64 + lane)*8;
      lf[fn] = *(const bf16x8*)(Wlsw + o);
      rf[fn] = *(const bf16x8*)(Wrsw + o);
    }
    #pragma unroll
    for (int fm=0; fm<2; fm++)
      #pragma unroll
      for (int fn=0; fn<4; fn++){
        accQ[fm][fn] = __builtin_amdgcn_mfma_f32_16x16x32_bf16(af[fm], lf[fn], accQ[fm][fn], 0,0,0);
        accK[fm][fn] = __builtin_amdgcn_mfma_f32_16x16x32_bf16(af[fm], rf[fn], accK[fm][fn], 0,0,0);
      }
  }

  // epilogue: +bias -> int8. C/D: col=lane&15, row=(lane>>4)*4+r
  #pragma unroll
  for (int fn=0; fn<4; fn++){
    int col = C0 + fn*16 + (lane&15);
    float blv = bl[col], brv = br[col];
    #pragma unroll
    for (int fm=0; fm<2; fm++){
      int row0 = rc*256 + wv*32 + fm*16 + ((lane>>4)<<2);
      #pragma unroll
      for (int r=0; r<4; r++){
        size_t o = (size_t)(row0+r)*HID + col;
        int qv = (int)rintf((accQ[fm][fn][r] + blv) * QINV);
        int kv = (int)rintf((accK[fm][fn][r] + brv) * QINV);
        Qi8[o]  = (signed char)min(127, max(-127, qv));
        K1i8[o] = (signed char)min(127, max(-127, kv));
      }
    }
  }
}

// T[n][t] = (Qi8[n] . k2q[t]) * QDELTA * k2scale
__global__ __launch_bounds__(256) void tdot_kernel(
    const signed char* __restrict__ Qi8, const signed char* __restrict__ k2q,
    const float* __restrict__ k2scale, float* __restrict__ T)
{
  __shared__ unsigned int k2s[ETN*64];
  for (int i=threadIdx.x; i<ETN*64; i+=256)
    k2s[i] = ((const unsigned int*)k2q)[i];
  __syncthreads();

  int tid = threadIdx.x;
  int sl = tid & 15;
  int n = blockIdx.x*16 + (tid>>4);
  u32x4 q  = ((const u32x4*)(Qi8 + (size_t)n*HID))[sl];
  u32x4 c0 = ((const u32x4*)(k2s))[sl];
  u32x4 c1 = ((const u32x4*)(k2s + 64))[sl];
  u32x4 c2 = ((const u32x4*)(k2s + 128))[sl];
  int a0=0, a1=0, a2=0;
  #pragma unroll
  for (int w2=0; w2<4; w2++){
    dot4i8(a0, q[w2], c0[w2]);
    dot4i8(a1, q[w2], c1[w2]);
    dot4i8(a2, q[w2], c2[w2]);
  }
  #pragma unroll
  for (int m=1;m<16;m<<=1){
    a0 += __shfl_xor(a0, m);
    a1 += __shfl_xor(a1, m);
    a2 += __shfl_xor(a2, m);
  }
  if (sl==0){
    float sc = QDELTA * k2scale[0];
    f32x4 tv; tv[0]=a0*sc; tv[1]=a1*sc; tv[2]=a2*sc; tv[3]=0.f;
    *(f32x4*)(T + (size_t)n*4) = tv;
  }
}

// fused edge pass: 16-lane groups, 8 edges/group; tail spread over all 16 lanes
// (lane sl: edge j=sl&7, role=sl>>3; role 0 adds ex to seg[2d], role 1 adds
// ex*score to seg[2d+1]) -> ONE atomic instruction per wave, 64 active lanes.
__global__ __launch_bounds__(256) void edge_attn(
    const signed char* __restrict__ Qi8, const signed char* __restrict__ K1i8,
    const float* __restrict__ T,
    const int* __restrict__ src, const int* __restrict__ dst, const int* __restrict__ ety,
    const float* __restrict__ scores,
    float* __restrict__ seg)
{
  // 4000 blocks; XCD x (= bid&7) handles graphs {x, x+8, x+16, x+24}:
  // per-graph Q+K1 int8 = 1 MB -> resident in that XCD's 4 MB L2.
  int bid = blockIdx.x;
  int xcd = bid & 7;
  int slot = bid >> 3;            // 0..499
  int grp = slot / 125;           // 0..3
  int within = slot - grp*125;    // 0..124
  int graph = grp*8 + xcd;

  int tid = threadIdx.x;
  int sl = tid & 15;
  int g = tid >> 4;               // 0..15
  int e0 = graph*EPER + within*128 + g*8;

  int4 sa = *(const int4*)(src + e0);
  int4 sb = *(const int4*)(src + e0 + 4);
  int4 da = *(const int4*)(dst + e0);
  int4 db = *(const int4*)(dst + e0 + 4);
  int4 ta = *(const int4*)(ety + e0);
  int4 tb = *(const int4*)(ety + e0 + 4);

  u32x4 qv[8], kv[8];
  #pragma unroll
  for (int j=0; j<8; j++){
    int dn = sel8(da, db, j);
    int sn = sel8(sa, sb, j);
    qv[j] = ((const u32x4*)(Qi8  + (size_t)dn*HID))[sl];
    kv[j] = ((const u32x4*)(K1i8 + (size_t)sn*HID))[sl];
  }

  int ac[8];
  #pragma unroll
  for (int j=0; j<8; j++) ac[j] = 0;
  #pragma unroll
  for (int j=0; j<8; j++)
    #pragma unroll
    for (int w2=0; w2<4; w2++)
      dot4i8(ac[j], qv[j][w2], kv[j][w2]);
  #pragma unroll
  for (int j=0; j<8; j++)
    #pragma unroll
    for (int m=1; m<16; m<<=1)
      ac[j] += __shfl_xor(ac[j], m);

  // after butterfly, all 16 lanes hold all 8 sums
  {
    int j = sl & 7;
    int role = sl >> 3;
    int dn = sel8(da, db, j);
    int sn = sel8(sa, sb, j);
    int tn = sel8(ta, tb, j);
    float av = (float)ac[0];
    av = (j==1) ? (float)ac[1] : av;
    av = (j==2) ? (float)ac[2] : av;
    av = (j==3) ? (float)ac[3] : av;
    av = (j==4) ? (float)ac[4] : av;
    av = (j==5) ? (float)ac[5] : av;
    av = (j==6) ? (float)ac[6] : av;
    av = (j==7) ? (float)ac[7] : av;
    const float DD = QDELTA*QDELTA;
    float ex = expf((av*DD + T[(size_t)dn*4 + tn]) * 0.0625f);
    float val = role ? ex * scores[sn] : ex;
    atomicAdd(&seg[2*dn + role], val);
  }
}

// per-graph candidate logits, log-softmax, CE; loss accumulated into out[0]
__global__ __launch_bounds__(128) void logits_kernel(
    const float* __restrict__ seg,
    const int* __restrict__ cand, const int* __restrict__ label,
    float* __restrict__ out)
{
  __shared__ float red[128];
  __shared__ float lvals[CN];
  int b = blockIdx.x;
  int t = threadIdx.x;
  float v = -FLT_MAX;
  if (t < CN){
    int node = cand[b*CN + t];
    float ss = seg[2*node];
    float u = (ss > 0.0f) ? (seg[2*node+1]/ss) : 0.0f;
    lvals[t] = u;
    out[1 + b*CN + t] = u;
    v = u;
  }
  red[t] = v; __syncthreads();
  for (int sd=64; sd>0; sd>>=1){
    if (t < sd) red[t] = fmaxf(red[t], red[t+sd]);
    __syncthreads();
  }
  float mx = red[0];
  __syncthreads();
  float sv = (t < CN) ? expf(lvals[t]-mx) : 0.0f;
  red[t] = sv; __syncthreads();
  for (int sd=64; sd>0; sd>>=1){
    if (t < sd) red[t] += red[t+sd];
    __syncthreads();
  }
  if (t==0){
    float lse = mx + logf(red[0]);
    atomicAdd(out, -(lvals[label[b]] - lse));
  }
}

extern "C" void kernel_launch(void* const* d_in, const int* in_sizes, int n_in,
                              void* d_out, int out_size, void* d_ws, size_t ws_size,
                              hipStream_t stream) {
  const float* emb      = (const float*)d_in[0];
  const float* scores   = (const float*)d_in[1];
  const float* Wl       = (const float*)d_in[2];
  const float* blb      = (const float*)d_in[3];
  const float* Wr       = (const float*)d_in[4];
  const float* brb      = (const float*)d_in[5];
  const float* We       = (const float*)d_in[6];
  const float* be       = (const float*)d_in[7];
  const float* edge_emb = (const float*)d_in[8];
  const int* src   = (const int*)d_in[9];
  const int* dst   = (const int*)d_in[10];
  const int* ety   = (const int*)d_in[11];
  const int* cand  = (const int*)d_in[12];
  const int* label = (const int*)d_in[13];
  float* out = (float*)d_out;

  char* w = (char*)d_ws;
  size_t off = 0;
  auto alloc = [&](size_t bytes)->char* {
    char* p = w + off; off += (bytes + 255) & ~(size_t)255; return p;
  };
  signed char*    Qi8  = (signed char*)alloc((size_t)NTOT*HID);        // 16 MB
  signed char*    K1i8 = (signed char*)alloc((size_t)NTOT*HID);        // 16 MB
  unsigned short* Wlsw = (unsigned short*)alloc((size_t)HID*HID*2);
  unsigned short* Wrsw = (unsigned short*)alloc((size_t)HID*HID*2);
  signed char*    k2q  = (signed char*)alloc((size_t)ETN*HID);
  float* k2scale = (float*)alloc(4);
  float* T      = (float*)alloc((size_t)NTOT*4*4);                     // 1 MB
  float* seg    = (float*)alloc((size_t)NTOT*8);                       // 512 KB
  (void)ws_size; (void)in_sizes; (void)n_in; (void)out_size;

  setup_kernel<<<dim3(565), dim3(256), 0, stream>>>(Wl, Wr, We, be, edge_emb,
                                                    Wlsw, Wrsw, k2q, k2scale, seg, out);
  gemm_qk<<<dim3(1000), dim3(512), 0, stream>>>(emb, Wlsw, Wrsw, blb, brb, Qi8, K1i8);
  tdot_kernel<<<dim3(NTOT/16), dim3(256), 0, stream>>>(Qi8, k2q, k2scale, T);
  edge_attn<<<dim3(ETOT/128), dim3(256), 0, stream>>>(Qi8, K1i8, T, src, dst, ety, scores,
                                                      seg);
  logits_kernel<<<dim3(NB), dim3(128), 0, stream>>>(seg, cand, label, out);
}

// Round 8
// 192.268 us; speedup vs baseline: 1.1572x; 1.1572x over previous
//
#include <hip/hip_runtime.h>
#include <hip/hip_bf16.h>
#include <float.h>
#include <math.h>

#define NB 32
#define NPER 2000
#define EPER 16000
#define HID 256
#define EFD 20
#define ETN 3
#define CN 100
#define NTOT (NB*NPER)   // 64000
#define ETOT (NB*EPER)   // 512000

#define QDELTA (6.0f/127.0f)        // int8 quant step for Q/K1 (elems ~N(0,1))
#define QINV   (127.0f/6.0f)

using f32x4  = __attribute__((ext_vector_type(4))) float;
using bf16x8 = __attribute__((ext_vector_type(8))) short;
using ushort8= __attribute__((ext_vector_type(8))) unsigned short;
using u32x4  = __attribute__((ext_vector_type(4))) unsigned int;

__device__ __forceinline__ unsigned short f2bf(float f){
  union{float f; unsigned int i;}v; v.f=f; unsigned int x=v.i;
  return (unsigned short)((x + 0x7fffu + ((x>>16)&1u)) >> 16);
}
__device__ __forceinline__ unsigned int cvt_pk_bf16(float lo, float hi){
  unsigned int r;
  asm("v_cvt_pk_bf16_f32 %0, %1, %2" : "=v"(r) : "v"(lo), "v"(hi));
  return r;
}
__device__ __forceinline__ void dot4i8(int& acc, unsigned int a, unsigned int b){
  asm("v_dot4_i32_i8 %0, %1, %2, %0" : "+v"(acc) : "v"(a), "v"(b));
}
__device__ __forceinline__ int sel4(int4 v, int i){
  int r = v.x;
  r = (i==1) ? v.y : r;
  r = (i==2) ? v.z : r;
  r = (i==3) ? v.w : r;
  return r;
}
__device__ __forceinline__ int sel8(int4 a, int4 b, int i){
  int lo = sel4(a, i&3);
  int hi = sel4(b, i&3);
  return (i&4) ? hi : lo;
}

// ---- setup: zero seg/out0; swizzle-convert Wl/Wr -> bf16 frag layout; k2 -> int8.
// seg layout: seg[2n] = sum(ex), seg[2n+1] = sum(ex*score)
__global__ __launch_bounds__(256) void setup_kernel(
    const float* __restrict__ Wl, const float* __restrict__ Wr,
    const float* __restrict__ We, const float* __restrict__ be,
    const float* __restrict__ edge_emb,
    unsigned short* __restrict__ Wlsw, unsigned short* __restrict__ Wrsw,
    signed char* __restrict__ k2q, float* __restrict__ k2scale,
    float* __restrict__ seg, float* __restrict__ out)
{
  __shared__ float k2f[ETN*HID];
  __shared__ float redmax[256];
  int b = blockIdx.x, t = threadIdx.x;
  if (b < 500) {
    int i = b*256 + t;            // 0..127999 = 2*NTOT
    seg[i] = 0.0f;
    if (i == 0) out[0] = 0.0f;
  } else if (b < 564) {
    int u = (b-500)*256 + t;       // 0..16383 units of 8 elems
    int mat  = u >> 13;
    int v    = u & 8191;
    int cblk = v >> 9;
    int r    = v & 511;
    int kblk = r >> 6;
    int lane = r & 63;
    int col  = (cblk<<4) | (lane&15);
    int kk   = (kblk<<5) | ((lane>>4)<<3);
    const float* Wsrc = mat ? Wr : Wl;
    const f32x4* p = (const f32x4*)(Wsrc + col*HID + kk);
    f32x4 x0 = p[0], x1 = p[1];
    ushort8 w;
    w[0]=f2bf(x0[0]); w[1]=f2bf(x0[1]); w[2]=f2bf(x0[2]); w[3]=f2bf(x0[3]);
    w[4]=f2bf(x1[0]); w[5]=f2bf(x1[1]); w[6]=f2bf(x1[2]); w[7]=f2bf(x1[3]);
    *(ushort8*)((mat ? Wrsw : Wlsw) + (size_t)v*8) = w;
  } else {
    int j = t;
    float lmax = 0.0f;
    for (int ty=0; ty<ETN; ty++){
      float acc = be[j];
      for (int f=0; f<EFD; f++){
        float x = edge_emb[ty*EFD+f];
        float g = 0.5f*x*(1.0f + erff(x*0.7071067811865476f));
        acc += g * We[j*EFD+f];
      }
      k2f[ty*HID + j] = acc;
      lmax = fmaxf(lmax, fabsf(acc));
    }
    redmax[t] = lmax; __syncthreads();
    for (int sd=128; sd>0; sd>>=1){
      if (t < sd) redmax[t] = fmaxf(redmax[t], redmax[t+sd]);
      __syncthreads();
    }
    float d2 = fmaxf(redmax[0], 1e-20f) * (1.0f/127.0f);
    for (int ty=0; ty<ETN; ty++){
      int qv = (int)rintf(k2f[ty*HID+j] / d2);
      qv = min(127, max(-127, qv));
      k2q[ty*HID + j] = (signed char)qv;
    }
    if (t == 0) k2scale[0] = d2;
  }
}

// Q = h@Wl^T+bl ; K1 = h@Wr^T+br -> int8. Block = 64 rows x 256 cols of both.
// Whole 64x256 A-tile staged ONCE into fragment-major LDS (frag reads are
// contiguous 1KB sweeps -> zero bank conflicts), ONE barrier, then 8
// free-running k-blocks of MFMA. W-frags direct from L2-resident swizzled global.
__global__ __launch_bounds__(512) void gemm_qk(
    const float* __restrict__ h,
    const unsigned short* __restrict__ Wlsw, const unsigned short* __restrict__ Wrsw,
    const float* __restrict__ bl, const float* __restrict__ br,
    signed char* __restrict__ Qi8, signed char* __restrict__ K1i8)
{
  // As[g][kblk][lane][8]: g = row>>4 (0..3), kblk = k>>5 (0..7),
  // lane = (row&15) | (((k>>3)&3)<<4), elem = k&7
  __shared__ unsigned short As[4*8*64*8];   // 32 KB

  int bm = blockIdx.x;          // 0..999
  int tid = threadIdx.x;
  int lane = tid & 63;
  int wv = tid >> 6;            // 8 waves
  int wm = wv >> 2;             // 0..1 : 32-row half
  int wn = wv & 3;              // 0..3 : 64-col slice

  const float* Arow = h + (size_t)bm*64*HID;

  // stage: 2048 chunks of 8 elems; 4 per thread; 32 consecutive tids = one row (1KB)
  #pragma unroll
  for (int i=0; i<4; i++){
    int c   = i*512 + tid;
    int row = c >> 5;
    int kc  = c & 31;           // 8-col chunk
    const float* p = Arow + row*HID + kc*8;
    f32x4 x0 = *(const f32x4*)p;
    f32x4 x1 = *(const f32x4*)(p + 4);
    u32x4 aw;
    aw[0] = cvt_pk_bf16(x0[0], x0[1]);
    aw[1] = cvt_pk_bf16(x0[2], x0[3]);
    aw[2] = cvt_pk_bf16(x1[0], x1[1]);
    aw[3] = cvt_pk_bf16(x1[2], x1[3]);
    int g   = row >> 4;
    int kb  = kc >> 2;
    int sub = (row & 15) | ((kc & 3) << 4);
    *(u32x4*)(&As[(((g*8 + kb)*64) + sub)*8]) = aw;
  }
  __syncthreads();

  f32x4 accQ[2][4], accK[2][4];
  #pragma unroll
  for(int i=0;i<2;i++)
    #pragma unroll
    for(int j=0;j<4;j++)
      #pragma unroll
      for(int r=0;r<4;r++){ accQ[i][j][r]=0.0f; accK[i][j][r]=0.0f; }

  #pragma unroll
  for (int kblk = 0; kblk < 8; ++kblk) {
    bf16x8 af[2], lf[4], rf[4];
    #pragma unroll
    for (int fm=0; fm<2; fm++){
      int g = wm*2 + fm;
      af[fm] = *(const bf16x8*)(&As[(((g*8 + kblk)*64) + lane)*8]);
    }
    #pragma unroll
    for (int fn=0; fn<4; fn++){
      size_t o = ((size_t)((wn*4 + fn)*8 + kblk)*64 + lane)*8;
      lf[fn] = *(const bf16x8*)(Wlsw + o);
      rf[fn] = *(const bf16x8*)(Wrsw + o);
    }
    #pragma unroll
    for (int fm=0; fm<2; fm++)
      #pragma unroll
      for (int fn=0; fn<4; fn++){
        accQ[fm][fn] = __builtin_amdgcn_mfma_f32_16x16x32_bf16(af[fm], lf[fn], accQ[fm][fn], 0,0,0);
        accK[fm][fn] = __builtin_amdgcn_mfma_f32_16x16x32_bf16(af[fm], rf[fn], accK[fm][fn], 0,0,0);
      }
  }

  // epilogue: +bias -> int8. C/D: col=lane&15, row=(lane>>4)*4+r
  #pragma unroll
  for (int fn=0; fn<4; fn++){
    int col = wn*64 + fn*16 + (lane&15);
    float blv = bl[col], brv = br[col];
    #pragma unroll
    for (int fm=0; fm<2; fm++){
      int row0 = bm*64 + wm*32 + fm*16 + ((lane>>4)<<2);
      #pragma unroll
      for (int r=0; r<4; r++){
        size_t o = (size_t)(row0+r)*HID + col;
        int qv = (int)rintf((accQ[fm][fn][r] + blv) * QINV);
        int kv = (int)rintf((accK[fm][fn][r] + brv) * QINV);
        Qi8[o]  = (signed char)min(127, max(-127, qv));
        K1i8[o] = (signed char)min(127, max(-127, kv));
      }
    }
  }
}

// T[n][t] = (Qi8[n] . k2q[t]) * QDELTA * k2scale
__global__ __launch_bounds__(256) void tdot_kernel(
    const signed char* __restrict__ Qi8, const signed char* __restrict__ k2q,
    const float* __restrict__ k2scale, float* __restrict__ T)
{
  __shared__ unsigned int k2s[ETN*64];
  for (int i=threadIdx.x; i<ETN*64; i+=256)
    k2s[i] = ((const unsigned int*)k2q)[i];
  __syncthreads();

  int tid = threadIdx.x;
  int sl = tid & 15;
  int n = blockIdx.x*16 + (tid>>4);
  u32x4 q  = ((const u32x4*)(Qi8 + (size_t)n*HID))[sl];
  u32x4 c0 = ((const u32x4*)(k2s))[sl];
  u32x4 c1 = ((const u32x4*)(k2s + 64))[sl];
  u32x4 c2 = ((const u32x4*)(k2s + 128))[sl];
  int a0=0, a1=0, a2=0;
  #pragma unroll
  for (int w2=0; w2<4; w2++){
    dot4i8(a0, q[w2], c0[w2]);
    dot4i8(a1, q[w2], c1[w2]);
    dot4i8(a2, q[w2], c2[w2]);
  }
  #pragma unroll
  for (int m=1;m<16;m<<=1){
    a0 += __shfl_xor(a0, m);
    a1 += __shfl_xor(a1, m);
    a2 += __shfl_xor(a2, m);
  }
  if (sl==0){
    float sc = QDELTA * k2scale[0];
    f32x4 tv; tv[0]=a0*sc; tv[1]=a1*sc; tv[2]=a2*sc; tv[3]=0.f;
    *(f32x4*)(T + (size_t)n*4) = tv;
  }
}

// fused edge pass: 16-lane groups, 8 edges/group; tail spread over all 16 lanes
// (lane sl: edge j=sl&7, role=sl>>3) -> ONE atomic instruction per wave.
__global__ __launch_bounds__(256) void edge_attn(
    const signed char* __restrict__ Qi8, const signed char* __restrict__ K1i8,
    const float* __restrict__ T,
    const int* __restrict__ src, const int* __restrict__ dst, const int* __restrict__ ety,
    const float* __restrict__ scores,
    float* __restrict__ seg)
{
  // 4000 blocks; XCD x (= bid&7) handles graphs {x, x+8, x+16, x+24}:
  // per-graph Q+K1 int8 = 1 MB -> resident in that XCD's 4 MB L2.
  int bid = blockIdx.x;
  int xcd = bid & 7;
  int slot = bid >> 3;            // 0..499
  int grp = slot / 125;           // 0..3
  int within = slot - grp*125;    // 0..124
  int graph = grp*8 + xcd;

  int tid = threadIdx.x;
  int sl = tid & 15;
  int g = tid >> 4;               // 0..15
  int e0 = graph*EPER + within*128 + g*8;

  int4 sa = *(const int4*)(src + e0);
  int4 sb = *(const int4*)(src + e0 + 4);
  int4 da = *(const int4*)(dst + e0);
  int4 db = *(const int4*)(dst + e0 + 4);
  int4 ta = *(const int4*)(ety + e0);
  int4 tb = *(const int4*)(ety + e0 + 4);

  u32x4 qv[8], kv[8];
  #pragma unroll
  for (int j=0; j<8; j++){
    int dn = sel8(da, db, j);
    int sn = sel8(sa, sb, j);
    qv[j] = ((const u32x4*)(Qi8  + (size_t)dn*HID))[sl];
    kv[j] = ((const u32x4*)(K1i8 + (size_t)sn*HID))[sl];
  }

  int ac[8];
  #pragma unroll
  for (int j=0; j<8; j++) ac[j] = 0;
  #pragma unroll
  for (int j=0; j<8; j++)
    #pragma unroll
    for (int w2=0; w2<4; w2++)
      dot4i8(ac[j], qv[j][w2], kv[j][w2]);
  #pragma unroll
  for (int j=0; j<8; j++)
    #pragma unroll
    for (int m=1; m<16; m<<=1)
      ac[j] += __shfl_xor(ac[j], m);

  // after butterfly, all 16 lanes hold all 8 sums
  {
    int j = sl & 7;
    int role = sl >> 3;
    int dn = sel8(da, db, j);
    int sn = sel8(sa, sb, j);
    int tn = sel8(ta, tb, j);
    float av = (float)ac[0];
    av = (j==1) ? (float)ac[1] : av;
    av = (j==2) ? (float)ac[2] : av;
    av = (j==3) ? (float)ac[3] : av;
    av = (j==4) ? (float)ac[4] : av;
    av = (j==5) ? (float)ac[5] : av;
    av = (j==6) ? (float)ac[6] : av;
    av = (j==7) ? (float)ac[7] : av;
    const float DD = QDELTA*QDELTA;
    float ex = expf((av*DD + T[(size_t)dn*4 + tn]) * 0.0625f);
    float val = role ? ex * scores[sn] : ex;
    atomicAdd(&seg[2*dn + role], val);
  }
}

// per-graph candidate logits, log-softmax, CE; loss accumulated into out[0]
__global__ __launch_bounds__(128) void logits_kernel(
    const float* __restrict__ seg,
    const int* __restrict__ cand, const int* __restrict__ label,
    float* __restrict__ out)
{
  __shared__ float red[128];
  __shared__ float lvals[CN];
  int b = blockIdx.x;
  int t = threadIdx.x;
  float v = -FLT_MAX;
  if (t < CN){
    int node = cand[b*CN + t];
    float ss = seg[2*node];
    float u = (ss > 0.0f) ? (seg[2*node+1]/ss) : 0.0f;
    lvals[t] = u;
    out[1 + b*CN + t] = u;
    v = u;
  }
  red[t] = v; __syncthreads();
  for (int sd=64; sd>0; sd>>=1){
    if (t < sd) red[t] = fmaxf(red[t], red[t+sd]);
    __syncthreads();
  }
  float mx = red[0];
  __syncthreads();
  float sv = (t < CN) ? expf(lvals[t]-mx) : 0.0f;
  red[t] = sv; __syncthreads();
  for (int sd=64; sd>0; sd>>=1){
    if (t < sd) red[t] += red[t+sd];
    __syncthreads();
  }
  if (t==0){
    float lse = mx + logf(red[0]);
    atomicAdd(out, -(lvals[label[b]] - lse));
  }
}

extern "C" void kernel_launch(void* const* d_in, const int* in_sizes, int n_in,
                              void* d_out, int out_size, void* d_ws, size_t ws_size,
                              hipStream_t stream) {
  const float* emb      = (const float*)d_in[0];
  const float* scores   = (const float*)d_in[1];
  const float* Wl       = (const float*)d_in[2];
  const float* blb      = (const float*)d_in[3];
  const float* Wr       = (const float*)d_in[4];
  const float* brb      = (const float*)d_in[5];
  const float* We       = (const float*)d_in[6];
  const float* be       = (const float*)d_in[7];
  const float* edge_emb = (const float*)d_in[8];
  const int* src   = (const int*)d_in[9];
  const int* dst   = (const int*)d_in[10];
  const int* ety   = (const int*)d_in[11];
  const int* cand  = (const int*)d_in[12];
  const int* label = (const int*)d_in[13];
  float* out = (float*)d_out;

  char* w = (char*)d_ws;
  size_t off = 0;
  auto alloc = [&](size_t bytes)->char* {
    char* p = w + off; off += (bytes + 255) & ~(size_t)255; return p;
  };
  signed char*    Qi8  = (signed char*)alloc((size_t)NTOT*HID);        // 16 MB
  signed char*    K1i8 = (signed char*)alloc((size_t)NTOT*HID);        // 16 MB
  unsigned short* Wlsw = (unsigned short*)alloc((size_t)HID*HID*2);
  unsigned short* Wrsw = (unsigned short*)alloc((size_t)HID*HID*2);
  signed char*    k2q  = (signed char*)alloc((size_t)ETN*HID);
  float* k2scale = (float*)alloc(4);
  float* T      = (float*)alloc((size_t)NTOT*4*4);                     // 1 MB
  float* seg    = (float*)alloc((size_t)NTOT*8);                       // 512 KB
  (void)ws_size; (void)in_sizes; (void)n_in; (void)out_size;

  setup_kernel<<<dim3(565), dim3(256), 0, stream>>>(Wl, Wr, We, be, edge_emb,
                                                    Wlsw, Wrsw, k2q, k2scale, seg, out);
  gemm_qk<<<dim3(1000), dim3(512), 0, stream>>>(emb, Wlsw, Wrsw, blb, brb, Qi8, K1i8);
  tdot_kernel<<<dim3(NTOT/16), dim3(256), 0, stream>>>(Qi8, k2q, k2scale, T);
  edge_attn<<<dim3(ETOT/128), dim3(256), 0, stream>>>(Qi8, K1i8, T, src, dst, ety, scores,
                                                      seg);
  logits_kernel<<<dim3(NB), dim3(128), 0, stream>>>(seg, cand, label, out);
}